// Round 13
// baseline (365.276 us; speedup 1.0000x reference)
//
#include <hip/hip_runtime.h>
#include <math.h>

#define NH 4
#define NF 64
#define NM 32
#define NT 16  // nodes per block in k_proj
#define SC 32  // elements per thread in k_scan (supports N <= 32768)

__device__ __forceinline__ float softplusf(float v){ return fmaxf(v, 0.f) + log1pf(expf(-fabsf(v))); }
__device__ __forceinline__ float sigmoidf_(float v){ return 1.f / (1.f + expf(-v)); }

// ---------------- K0: zero deg + cursor ----------------
__global__ void k_zero(int* __restrict__ z, int n) {
  int i = blockIdx.x * blockDim.x + threadIdx.x;
  if (i < n) z[i] = 0;
}

// ---------------- K0b: degree count ----------------
__global__ void k_count(const int* __restrict__ ei, int* __restrict__ deg, int E) {
  int e = blockIdx.x * blockDim.x + threadIdx.x;
  if (e < E) atomicAdd(&deg[ei[E + e]], 1);
}

// ---------------- K1: tiled node pass (split: blockIdx.y = matrix) ----------------
// grid = (ceil(N/NT), 3); block = 256 = 4 heads x 64 cols.
// f0 loops FULLY UNROLLED so all LDS/global offsets are compile-time immediates.
// mat 0: ep (LDS) + sr/st + decay/temp MLPs. mat 1/2: rp/tp into pt[n][g][8].
__global__ __launch_bounds__(256)
void k_proj(const float* __restrict__ x,
            const float* __restrict__ Wp, const float* __restrict__ Wr, const float* __restrict__ Wt,
            const float* __restrict__ rsc, const float* __restrict__ tsc,
            const float* __restrict__ dW1, const float* __restrict__ db1,
            const float* __restrict__ dw2, const float* __restrict__ db2,
            const float* __restrict__ tW1, const float* __restrict__ tb1,
            const float* __restrict__ tw2, const float* __restrict__ tb2,
            const float* __restrict__ rdls, const float* __restrict__ rtb,
            float* __restrict__ pt,
            float* __restrict__ sr, float* __restrict__ st,
            float* __restrict__ doff, float* __restrict__ toff, int N) {
  int n0 = blockIdx.x * NT;
  int mat = blockIdx.y;
  int tid = threadIdx.x;
  int h = tid >> 6, g = tid & 63;
  __shared__ float xs[NT][NF];        // 4 KB
  __shared__ float eps[NT][NH][NF];   // 16 KB (only used by mat 0)

  {
    // 256 float4 = whole x tile; thread i loads one float4
    int n = (tid * 4) >> 6, f = (tid * 4) & 63;
    float4 v = make_float4(0.f, 0.f, 0.f, 0.f);
    if (n0 + n < N) v = *(const float4*)(x + (size_t)(n0 + n) * NF + f);
    *(float4*)&xs[n][f] = v;
  }
  __syncthreads();

  const float* W = (mat == 0 ? Wp : (mat == 1 ? Wr : Wt)) + (size_t)h * NF * NF + g;
  float acc[NT];
  #pragma unroll
  for (int n = 0; n < NT; ++n) acc[n] = 0.f;

  #pragma unroll
  for (int f0 = 0; f0 < NF; f0 += 4) {
    float w0 = W[(f0 + 0) * NF];
    float w1 = W[(f0 + 1) * NF];
    float w2 = W[(f0 + 2) * NF];
    float w3 = W[(f0 + 3) * NF];
    #pragma unroll
    for (int n = 0; n < NT; ++n) {
      float4 xv = *(const float4*)&xs[n][f0];
      acc[n] += xv.x * w0 + xv.y * w1 + xv.z * w2 + xv.w * w3;
    }
  }

  if (mat != 0) {
    // rp -> rows 0..3, tp -> rows 4..7 of pt[n][g][8]
    int row = (mat - 1) * NH + h;
    #pragma unroll
    for (int n = 0; n < NT; ++n)
      if (n0 + n < N) pt[(((size_t)(n0 + n)) * NF + g) * 8 + row] = acc[n];
    return;
  }

  // mat == 0: ep path
  #pragma unroll
  for (int n = 0; n < NT; ++n) eps[n][h][g] = acc[n];

  float rs = rsc[h * NF + g], ts = tsc[h * NF + g];
  for (int n = 0; n < NT; ++n) {
    float a = acc[n] * rs, b = acc[n] * ts;
    for (int off = 32; off; off >>= 1) { a += __shfl_xor(a, off); b += __shfl_xor(b, off); }
    if (g == 0 && n0 + n < N) { sr[(n0 + n) * NH + h] = a; st[(n0 + n) * NH + h] = b; }
  }
  __syncthreads();

  // MLPs: lanes 0..31 decay, 32..63 temp; fully-unrolled f0 loop
  int m = g & 31;
  bool isTemp = (g >= 32);
  const float* W1 = (isTemp ? tW1 : dW1) + (size_t)h * NF * NM + m;
  float bias = isTemp ? tb1[h * NM + m] : db1[h * NM + m];
  float w2v  = isTemp ? tw2[h * NM + m] : dw2[h * NM + m];
  float accm[NT];
  #pragma unroll
  for (int n = 0; n < NT; ++n) accm[n] = bias;
  #pragma unroll
  for (int f0 = 0; f0 < NF; f0 += 4) {
    float w0 = W1[(f0 + 0) * NM];
    float w1 = W1[(f0 + 1) * NM];
    float w2_ = W1[(f0 + 2) * NM];
    float w3 = W1[(f0 + 3) * NM];
    #pragma unroll
    for (int n = 0; n < NT; ++n) {
      float4 ev = *(const float4*)&eps[n][h][f0];
      accm[n] += ev.x * w0 + ev.y * w1 + ev.z * w2_ + ev.w * w3;
    }
  }
  for (int n = 0; n < NT; ++n) {
    float a = accm[n];
    float p = a * sigmoidf_(a) * w2v;  // silu * w2
    for (int off = 16; off; off >>= 1) p += __shfl_xor(p, off);
    if (m == 0 && n0 + n < N) {
      if (!isTemp) doff[(n0 + n) * NH + h] = p + db2[h] + softplusf(rdls[h]);
      else         toff[(n0 + n) * NH + h] = p + tb2[h] + rtb[h];
    }
  }
}

// ---------------- K2: exclusive prefix scan (thread-serial + one tree) ----------------
// 1024 threads x SC=32 elems. 20 barriers total (was 400).
__global__ void k_scan(const int* __restrict__ deg, int* __restrict__ start, int N) {
  __shared__ int sums[1024];
  int tid = threadIdx.x;
  int base = tid * SC;
  int local[SC];
  int s = 0;
  #pragma unroll
  for (int j = 0; j < SC; ++j) {
    int i = base + j;
    int v = (i < N) ? deg[i] : 0;
    local[j] = s;   // exclusive local prefix
    s += v;
  }
  sums[tid] = s;
  __syncthreads();
  for (int off = 1; off < 1024; off <<= 1) {
    int t = (tid >= off) ? sums[tid - off] : 0;
    __syncthreads();
    sums[tid] += t;
    __syncthreads();
  }
  int tbase = (tid > 0) ? sums[tid - 1] : 0;
  #pragma unroll
  for (int j = 0; j < SC; ++j) {
    int i = base + j;
    if (i < N) start[i] = tbase + local[j];
  }
  if (tid == 1023) start[N] = sums[1023];
}

// ---------------- K3: per-edge logits + gate, written in CSR order ----------------
__global__ void k_edge(const int* __restrict__ ei, const float* __restrict__ elen,
                       const float4* __restrict__ sr4, const float4* __restrict__ st4,
                       const float4* __restrict__ doff4, const float4* __restrict__ toff4,
                       const float* __restrict__ rtw,
                       const float* __restrict__ mixb, const float* __restrict__ mixs,
                       const int* __restrict__ start, int* __restrict__ cursor,
                       float4* __restrict__ crl, float4* __restrict__ ctl, float4* __restrict__ cgv,
                       int* __restrict__ snd, int E) {
  int e = blockIdx.x * blockDim.x + threadIdx.x;
  if (e >= E) return;
  int s = ei[e], r = ei[E + e];
  float len = elen[e];
  int slot = start[r] + atomicAdd(&cursor[r], 1);
  float4 a = sr4[s], b = sr4[r], c = st4[s], d = st4[r], dof = doff4[r], tof = toff4[r];
  const float* ap = (const float*)&a; const float* bp = (const float*)&b;
  const float* cp = (const float*)&c; const float* dp = (const float*)&d;
  const float* dofp = (const float*)&dof; const float* tofp = (const float*)&tof;
  float rlv[NH], tlv[NH], gv[NH];
  #pragma unroll
  for (int h = 0; h < NH; ++h) {
    float temp = softplusf(tofp[h] + rtw[h] * len);
    rlv[h] = (ap[h] - bp[h] - dofp[h] * len) / (temp + 1e-4f);
    tlv[h] = cp[h] - dp[h];
    gv[h] = sigmoidf_(mixb[h] + mixs[h] * len);
  }
  crl[slot] = make_float4(rlv[0], rlv[1], rlv[2], rlv[3]);
  ctl[slot] = make_float4(tlv[0], tlv[1], tlv[2], tlv[3]);
  cgv[slot] = make_float4(gv[0], gv[1], gv[2], gv[3]);
  snd[slot] = s;
}

// ---------------- K4: per-receiver softmax + gather-aggregate + Wout + residual ----------------
__global__ __launch_bounds__(256)
void k_aggout(const int* __restrict__ start, const int* __restrict__ snd,
              const float4* __restrict__ crl, const float4* __restrict__ ctl, const float4* __restrict__ cgv,
              const float* __restrict__ pt, const float* __restrict__ x,
              const float* __restrict__ Wout, float* __restrict__ out, int N) {
  __shared__ float wout_s[NF * NF];
  __shared__ float coef_s[4][64][8];
  __shared__ int   snd_s[4][64];
  __shared__ float am_s[4][NF];
  int tid = threadIdx.x;
  {
    const float4* w4 = (const float4*)Wout;
    float4* s4 = (float4*)wout_s;
    for (int i = tid; i < NF * NF / 4; i += 256) s4[i] = w4[i];
  }
  __syncthreads();   // only block-wide barrier; everything after is wave-local
  int w = tid >> 6, g = tid & 63;
  int n = blockIdx.x * 4 + w;
  if (n >= N) return;
  int i0 = start[n], i1 = start[n + 1];

  // pass A: per-head max (edge-parallel, lane = edge)
  float rm[NH] = {-1e30f, -1e30f, -1e30f, -1e30f};
  float tm[NH] = {-1e30f, -1e30f, -1e30f, -1e30f};
  for (int i = i0 + g; i < i1; i += 64) {
    float4 rv = crl[i], tv = ctl[i];
    const float* rp_ = (const float*)&rv; const float* tp_ = (const float*)&tv;
    #pragma unroll
    for (int h = 0; h < NH; ++h) { rm[h] = fmaxf(rm[h], rp_[h]); tm[h] = fmaxf(tm[h], tp_[h]); }
  }
  #pragma unroll
  for (int off = 32; off; off >>= 1)
    #pragma unroll
    for (int h = 0; h < NH; ++h) {
      rm[h] = fmaxf(rm[h], __shfl_xor(rm[h], off));
      tm[h] = fmaxf(tm[h], __shfl_xor(tm[h], off));
    }

  // pass B: per-head exp-sum
  float rs_[NH] = {0.f, 0.f, 0.f, 0.f}, ts_[NH] = {0.f, 0.f, 0.f, 0.f};
  for (int i = i0 + g; i < i1; i += 64) {
    float4 rv = crl[i], tv = ctl[i];
    const float* rp_ = (const float*)&rv; const float* tp_ = (const float*)&tv;
    #pragma unroll
    for (int h = 0; h < NH; ++h) { rs_[h] += expf(rp_[h] - rm[h]); ts_[h] += expf(tp_[h] - tm[h]); }
  }
  #pragma unroll
  for (int off = 32; off; off >>= 1)
    #pragma unroll
    for (int h = 0; h < NH; ++h) { rs_[h] += __shfl_xor(rs_[h], off); ts_[h] += __shfl_xor(ts_[h], off); }
  #pragma unroll
  for (int h = 0; h < NH; ++h) { rs_[h] = 1.f / (rs_[h] + 1e-9f); ts_[h] = 1.f / (ts_[h] + 1e-9f); }

  // pass C: coefficients (lane=edge) + gather-aggregate (lane=feature)
  float acc = 0.f;
  float sc1[NH] = {0.f, 0.f, 0.f, 0.f}, sc2[NH] = {0.f, 0.f, 0.f, 0.f};
  for (int base = i0; base < i1; base += 64) {
    int i = base + g;
    if (i < i1) {
      float4 rv = crl[i], tv = ctl[i], gv = cgv[i];
      const float* rp_ = (const float*)&rv; const float* tp_ = (const float*)&tv;
      const float* gp_ = (const float*)&gv;
      #pragma unroll
      for (int h = 0; h < NH; ++h) {
        float ar = expf(rp_[h] - rm[h]) * rs_[h];
        float at = expf(tp_[h] - tm[h]) * ts_[h];
        float gg = gp_[h];
        float ba = gg * ar + (1.f - gg) * at;
        float c1 = ba * gg, c2 = ba * (1.f - gg);
        coef_s[w][g][h] = c1; coef_s[w][g][4 + h] = c2;
        sc1[h] += c1; sc2[h] += c2;
      }
      snd_s[w][g] = snd[i];
    }
    int cnt = min(64, i1 - base);
    for (int j = 0; j < cnt; ++j) {
      int s = snd_s[w][j];
      const float4* b4 = (const float4*)(pt + ((size_t)s * NF + g) * 8);
      float4 rpv = b4[0], tpv = b4[1];
      const float* rpp = (const float*)&rpv; const float* tpp = (const float*)&tpv;
      #pragma unroll
      for (int h = 0; h < NH; ++h)
        acc += coef_s[w][j][h] * rpp[h] + coef_s[w][j][4 + h] * tpp[h];
    }
  }
  // reduce coefficient sums across the wave (each lane held its own edges' share)
  #pragma unroll
  for (int off = 32; off; off >>= 1)
    #pragma unroll
    for (int h = 0; h < NH; ++h) { sc1[h] += __shfl_xor(sc1[h], off); sc2[h] += __shfl_xor(sc2[h], off); }

  const float4* bn4 = (const float4*)(pt + ((size_t)n * NF + g) * 8);
  float4 rpn = bn4[0], tpn = bn4[1];
  const float* rnp = (const float*)&rpn; const float* tnp = (const float*)&tpn;
  #pragma unroll
  for (int h = 0; h < NH; ++h) acc -= sc1[h] * rnp[h] + sc2[h] * tnp[h];
  acc *= (1.f / NH);

  am_s[w][g] = acc;   // wave-local LDS; no block barrier needed
  float o = x[(size_t)n * NF + g];
  #pragma unroll 8
  for (int f = 0; f < NF; ++f) o += am_s[w][f] * wout_s[f * NF + g];
  out[(size_t)n * NF + g] = o;
}

extern "C" void kernel_launch(void* const* d_in, const int* in_sizes, int n_in,
                              void* d_out, int out_size, void* d_ws, size_t ws_size,
                              hipStream_t stream) {
  const float* x    = (const float*)d_in[0];
  const int*   ei   = (const int*)d_in[1];
  // d_in[2] = edge_vec, unused by the reference
  const float* elen = (const float*)d_in[3];
  const float* Wp   = (const float*)d_in[4];
  const float* Wr   = (const float*)d_in[5];
  const float* Wt   = (const float*)d_in[6];
  const float* rsc  = (const float*)d_in[7];
  const float* tsc  = (const float*)d_in[8];
  const float* rdls = (const float*)d_in[9];
  const float* rtb  = (const float*)d_in[10];
  const float* rtw  = (const float*)d_in[11];
  const float* mixb = (const float*)d_in[12];
  const float* mixs = (const float*)d_in[13];
  const float* dW1  = (const float*)d_in[14];
  const float* db1  = (const float*)d_in[15];
  const float* dw2  = (const float*)d_in[16];
  const float* db2  = (const float*)d_in[17];
  const float* tW1  = (const float*)d_in[18];
  const float* tb1  = (const float*)d_in[19];
  const float* tw2  = (const float*)d_in[20];
  const float* tb2  = (const float*)d_in[21];
  const float* Wout = (const float*)d_in[22];

  int N = in_sizes[0] / NF;
  int E = in_sizes[3];

  float* p = (float*)d_ws;
  float* pt   = p; p += (size_t)N * NF * 8;   // [n][g][8]
  float* sr   = p; p += (size_t)N * NH;
  float* st   = p; p += (size_t)N * NH;
  float* doff = p; p += (size_t)N * NH;
  float* toff = p; p += (size_t)N * NH;
  float* crl  = p; p += (size_t)E * NH;       // CSR-ordered radial logits
  float* ctl  = p; p += (size_t)E * NH;       // CSR-ordered tangential logits
  float* cgv  = p; p += (size_t)E * NH;       // CSR-ordered mix gate
  int* snd    = (int*)p; p += E;              // CSR-ordered sender ids
  int* deg    = (int*)p; p += N;
  int* cursor = (int*)p; p += N;
  int* startp = (int*)p; p += N + 1;

  // K0: zero deg + cursor (contiguous)
  k_zero<<<(2 * N + 255) / 256, 256, 0, stream>>>(deg, 2 * N);
  // K0b: degree count
  k_count<<<(E + 255) / 256, 256, 0, stream>>>(ei, deg, E);
  // K1: tiled node pass (split by matrix)
  {
    dim3 grid((N + NT - 1) / NT, 3);
    k_proj<<<grid, 256, 0, stream>>>(x, Wp, Wr, Wt, rsc, tsc, dW1, db1, dw2, db2,
                                     tW1, tb1, tw2, tb2, rdls, rtb,
                                     pt, sr, st, doff, toff, N);
  }
  // K2: scan degrees -> CSR starts
  k_scan<<<1, 1024, 0, stream>>>(deg, startp, N);
  // K3: per-edge logits into CSR slots
  k_edge<<<(E + 255) / 256, 256, 0, stream>>>(ei, elen, (const float4*)sr, (const float4*)st,
                                              (const float4*)doff, (const float4*)toff,
                                              rtw, mixb, mixs, startp, cursor,
                                              (float4*)crl, (float4*)ctl, (float4*)cgv, snd, E);
  // K4: softmax + aggregate + output
  k_aggout<<<(N + 3) / 4, 256, 0, stream>>>(startp, snd, (const float4*)crl, (const float4*)ctl,
                                            (const float4*)cgv, pt, x, Wout, (float*)d_out, N);
}

// Round 14
// 230.086 us; speedup vs baseline: 1.5876x; 1.5876x over previous
//
#include <hip/hip_runtime.h>
#include <math.h>

#define NH 4
#define NF 64
#define NM 32
#define NT 16  // nodes per block in k_proj
#define SC 32  // elements per thread in k_scan (supports N <= 32768)

__device__ __forceinline__ float softplusf(float v){ return fmaxf(v, 0.f) + log1pf(expf(-fabsf(v))); }
__device__ __forceinline__ float sigmoidf_(float v){ return 1.f / (1.f + expf(-v)); }

// ---------------- K0: zero deg + cursor ----------------
__global__ void k_zero(int* __restrict__ z, int n) {
  int i = blockIdx.x * blockDim.x + threadIdx.x;
  if (i < n) z[i] = 0;
}

// ---------------- K0b: degree count ----------------
__global__ void k_count(const int* __restrict__ ei, int* __restrict__ deg, int E) {
  int e = blockIdx.x * blockDim.x + threadIdx.x;
  if (e < E) atomicAdd(&deg[ei[E + e]], 1);
}

// ---------------- K1: tiled node pass (split: blockIdx.y = matrix) ----------------
// EXACT R12 structure (measured: 107us, 56 VGPR, occ 38%, VALU 75%).
// Moderate loop (no full unroll -> no register cliff). float4 xs/eps reads.
__global__ __launch_bounds__(256)
void k_proj(const float* __restrict__ x,
            const float* __restrict__ Wp, const float* __restrict__ Wr, const float* __restrict__ Wt,
            const float* __restrict__ rsc, const float* __restrict__ tsc,
            const float* __restrict__ dW1, const float* __restrict__ db1,
            const float* __restrict__ dw2, const float* __restrict__ db2,
            const float* __restrict__ tW1, const float* __restrict__ tb1,
            const float* __restrict__ tw2, const float* __restrict__ tb2,
            const float* __restrict__ rdls, const float* __restrict__ rtb,
            float* __restrict__ pt,
            float* __restrict__ sr, float* __restrict__ st,
            float* __restrict__ doff, float* __restrict__ toff, int N) {
  int n0 = blockIdx.x * NT;
  int mat = blockIdx.y;
  int tid = threadIdx.x;
  int h = tid >> 6, g = tid & 63;
  __shared__ float xs[NT][NF];        // 4 KB
  __shared__ float eps[NT][NH][NF];   // 16 KB (only used by mat 0)

  {
    // 256 float4 = whole x tile; thread i loads one float4
    int n = (tid * 4) >> 6, f = (tid * 4) & 63;
    float4 v = make_float4(0.f, 0.f, 0.f, 0.f);
    if (n0 + n < N) v = *(const float4*)(x + (size_t)(n0 + n) * NF + f);
    *(float4*)&xs[n][f] = v;
  }
  __syncthreads();

  const float* W = (mat == 0 ? Wp : (mat == 1 ? Wr : Wt)) + (size_t)h * NF * NF;
  float acc[NT];
  #pragma unroll
  for (int n = 0; n < NT; ++n) acc[n] = 0.f;

  for (int f0 = 0; f0 < NF; f0 += 4) {
    float w0 = W[(f0 + 0) * NF + g];
    float w1 = W[(f0 + 1) * NF + g];
    float w2 = W[(f0 + 2) * NF + g];
    float w3 = W[(f0 + 3) * NF + g];
    #pragma unroll
    for (int n = 0; n < NT; ++n) {
      float4 xv = *(const float4*)&xs[n][f0];
      acc[n] += xv.x * w0 + xv.y * w1 + xv.z * w2 + xv.w * w3;
    }
  }

  if (mat != 0) {
    // rp -> rows 0..3, tp -> rows 4..7 of pt[n][g][8]
    int row = (mat - 1) * NH + h;
    #pragma unroll
    for (int n = 0; n < NT; ++n)
      if (n0 + n < N) pt[(((size_t)(n0 + n)) * NF + g) * 8 + row] = acc[n];
    return;
  }

  // mat == 0: ep path
  #pragma unroll
  for (int n = 0; n < NT; ++n) eps[n][h][g] = acc[n];

  float rs = rsc[h * NF + g], ts = tsc[h * NF + g];
  for (int n = 0; n < NT; ++n) {
    float a = acc[n] * rs, b = acc[n] * ts;
    for (int off = 32; off; off >>= 1) { a += __shfl_xor(a, off); b += __shfl_xor(b, off); }
    if (g == 0 && n0 + n < N) { sr[(n0 + n) * NH + h] = a; st[(n0 + n) * NH + h] = b; }
  }
  __syncthreads();

  // MLPs: lanes 0..31 decay, 32..63 temp; float4 eps reads
  int m = g & 31;
  bool isTemp = (g >= 32);
  const float* W1 = isTemp ? tW1 : dW1;
  float bias = isTemp ? tb1[h * NM + m] : db1[h * NM + m];
  float w2v  = isTemp ? tw2[h * NM + m] : dw2[h * NM + m];
  float accm[NT];
  #pragma unroll
  for (int n = 0; n < NT; ++n) accm[n] = bias;
  for (int f0 = 0; f0 < NF; f0 += 4) {
    float w0 = W1[(h * NF + f0 + 0) * NM + m];
    float w1 = W1[(h * NF + f0 + 1) * NM + m];
    float w2_ = W1[(h * NF + f0 + 2) * NM + m];
    float w3 = W1[(h * NF + f0 + 3) * NM + m];
    #pragma unroll
    for (int n = 0; n < NT; ++n) {
      float4 ev = *(const float4*)&eps[n][h][f0];
      accm[n] += ev.x * w0 + ev.y * w1 + ev.z * w2_ + ev.w * w3;
    }
  }
  for (int n = 0; n < NT; ++n) {
    float a = accm[n];
    float p = a * sigmoidf_(a) * w2v;  // silu * w2
    for (int off = 16; off; off >>= 1) p += __shfl_xor(p, off);
    if (m == 0 && n0 + n < N) {
      if (!isTemp) doff[(n0 + n) * NH + h] = p + db2[h] + softplusf(rdls[h]);
      else         toff[(n0 + n) * NH + h] = p + tb2[h] + rtb[h];
    }
  }
}

// ---------------- K2: exclusive prefix scan (thread-serial + one tree) ----------------
// 1024 threads x SC=32 elems. 20 barriers total (saved ~40us vs 400-barrier version).
__global__ void k_scan(const int* __restrict__ deg, int* __restrict__ start, int N) {
  __shared__ int sums[1024];
  int tid = threadIdx.x;
  int base = tid * SC;
  int local[SC];
  int s = 0;
  #pragma unroll
  for (int j = 0; j < SC; ++j) {
    int i = base + j;
    int v = (i < N) ? deg[i] : 0;
    local[j] = s;   // exclusive local prefix
    s += v;
  }
  sums[tid] = s;
  __syncthreads();
  for (int off = 1; off < 1024; off <<= 1) {
    int t = (tid >= off) ? sums[tid - off] : 0;
    __syncthreads();
    sums[tid] += t;
    __syncthreads();
  }
  int tbase = (tid > 0) ? sums[tid - 1] : 0;
  #pragma unroll
  for (int j = 0; j < SC; ++j) {
    int i = base + j;
    if (i < N) start[i] = tbase + local[j];
  }
  if (tid == 1023) start[N] = sums[1023];
}

// ---------------- K3: per-edge logits + gate, written in CSR order ----------------
__global__ void k_edge(const int* __restrict__ ei, const float* __restrict__ elen,
                       const float4* __restrict__ sr4, const float4* __restrict__ st4,
                       const float4* __restrict__ doff4, const float4* __restrict__ toff4,
                       const float* __restrict__ rtw,
                       const float* __restrict__ mixb, const float* __restrict__ mixs,
                       const int* __restrict__ start, int* __restrict__ cursor,
                       float4* __restrict__ crl, float4* __restrict__ ctl, float4* __restrict__ cgv,
                       int* __restrict__ snd, int E) {
  int e = blockIdx.x * blockDim.x + threadIdx.x;
  if (e >= E) return;
  int s = ei[e], r = ei[E + e];
  float len = elen[e];
  int slot = start[r] + atomicAdd(&cursor[r], 1);
  float4 a = sr4[s], b = sr4[r], c = st4[s], d = st4[r], dof = doff4[r], tof = toff4[r];
  const float* ap = (const float*)&a; const float* bp = (const float*)&b;
  const float* cp = (const float*)&c; const float* dp = (const float*)&d;
  const float* dofp = (const float*)&dof; const float* tofp = (const float*)&tof;
  float rlv[NH], tlv[NH], gv[NH];
  #pragma unroll
  for (int h = 0; h < NH; ++h) {
    float temp = softplusf(tofp[h] + rtw[h] * len);
    rlv[h] = (ap[h] - bp[h] - dofp[h] * len) / (temp + 1e-4f);
    tlv[h] = cp[h] - dp[h];
    gv[h] = sigmoidf_(mixb[h] + mixs[h] * len);
  }
  crl[slot] = make_float4(rlv[0], rlv[1], rlv[2], rlv[3]);
  ctl[slot] = make_float4(tlv[0], tlv[1], tlv[2], tlv[3]);
  cgv[slot] = make_float4(gv[0], gv[1], gv[2], gv[3]);
  snd[slot] = s;
}

// ---------------- K4: per-receiver softmax + gather-aggregate + Wout + residual ----------------
__global__ __launch_bounds__(256)
void k_aggout(const int* __restrict__ start, const int* __restrict__ snd,
              const float4* __restrict__ crl, const float4* __restrict__ ctl, const float4* __restrict__ cgv,
              const float* __restrict__ pt, const float* __restrict__ x,
              const float* __restrict__ Wout, float* __restrict__ out, int N) {
  __shared__ float wout_s[NF * NF];
  __shared__ float coef_s[4][64][8];
  __shared__ int   snd_s[4][64];
  __shared__ float am_s[4][NF];
  int tid = threadIdx.x;
  {
    const float4* w4 = (const float4*)Wout;
    float4* s4 = (float4*)wout_s;
    for (int i = tid; i < NF * NF / 4; i += 256) s4[i] = w4[i];
  }
  __syncthreads();   // only block-wide barrier; everything after is wave-local
  int w = tid >> 6, g = tid & 63;
  int n = blockIdx.x * 4 + w;
  if (n >= N) return;
  int i0 = start[n], i1 = start[n + 1];

  // pass A: per-head max (edge-parallel, lane = edge)
  float rm[NH] = {-1e30f, -1e30f, -1e30f, -1e30f};
  float tm[NH] = {-1e30f, -1e30f, -1e30f, -1e30f};
  for (int i = i0 + g; i < i1; i += 64) {
    float4 rv = crl[i], tv = ctl[i];
    const float* rp_ = (const float*)&rv; const float* tp_ = (const float*)&tv;
    #pragma unroll
    for (int h = 0; h < NH; ++h) { rm[h] = fmaxf(rm[h], rp_[h]); tm[h] = fmaxf(tm[h], tp_[h]); }
  }
  #pragma unroll
  for (int off = 32; off; off >>= 1)
    #pragma unroll
    for (int h = 0; h < NH; ++h) {
      rm[h] = fmaxf(rm[h], __shfl_xor(rm[h], off));
      tm[h] = fmaxf(tm[h], __shfl_xor(tm[h], off));
    }

  // pass B: per-head exp-sum
  float rs_[NH] = {0.f, 0.f, 0.f, 0.f}, ts_[NH] = {0.f, 0.f, 0.f, 0.f};
  for (int i = i0 + g; i < i1; i += 64) {
    float4 rv = crl[i], tv = ctl[i];
    const float* rp_ = (const float*)&rv; const float* tp_ = (const float*)&tv;
    #pragma unroll
    for (int h = 0; h < NH; ++h) { rs_[h] += expf(rp_[h] - rm[h]); ts_[h] += expf(tp_[h] - tm[h]); }
  }
  #pragma unroll
  for (int off = 32; off; off >>= 1)
    #pragma unroll
    for (int h = 0; h < NH; ++h) { rs_[h] += __shfl_xor(rs_[h], off); ts_[h] += __shfl_xor(ts_[h], off); }
  #pragma unroll
  for (int h = 0; h < NH; ++h) { rs_[h] = 1.f / (rs_[h] + 1e-9f); ts_[h] = 1.f / (ts_[h] + 1e-9f); }

  // pass C: coefficients (lane=edge) + gather-aggregate (lane=feature)
  float acc = 0.f;
  float sc1[NH] = {0.f, 0.f, 0.f, 0.f}, sc2[NH] = {0.f, 0.f, 0.f, 0.f};
  for (int base = i0; base < i1; base += 64) {
    int i = base + g;
    if (i < i1) {
      float4 rv = crl[i], tv = ctl[i], gv = cgv[i];
      const float* rp_ = (const float*)&rv; const float* tp_ = (const float*)&tv;
      const float* gp_ = (const float*)&gv;
      #pragma unroll
      for (int h = 0; h < NH; ++h) {
        float ar = expf(rp_[h] - rm[h]) * rs_[h];
        float at = expf(tp_[h] - tm[h]) * ts_[h];
        float gg = gp_[h];
        float ba = gg * ar + (1.f - gg) * at;
        float c1 = ba * gg, c2 = ba * (1.f - gg);
        coef_s[w][g][h] = c1; coef_s[w][g][4 + h] = c2;
        sc1[h] += c1; sc2[h] += c2;
      }
      snd_s[w][g] = snd[i];
    }
    int cnt = min(64, i1 - base);
    for (int j = 0; j < cnt; ++j) {
      int s = snd_s[w][j];
      const float4* b4 = (const float4*)(pt + ((size_t)s * NF + g) * 8);
      float4 rpv = b4[0], tpv = b4[1];
      const float* rpp = (const float*)&rpv; const float* tpp = (const float*)&tpv;
      #pragma unroll
      for (int h = 0; h < NH; ++h)
        acc += coef_s[w][j][h] * rpp[h] + coef_s[w][j][4 + h] * tpp[h];
    }
  }
  // reduce coefficient sums across the wave (each lane held its own edges' share)
  #pragma unroll
  for (int off = 32; off; off >>= 1)
    #pragma unroll
    for (int h = 0; h < NH; ++h) { sc1[h] += __shfl_xor(sc1[h], off); sc2[h] += __shfl_xor(sc2[h], off); }

  const float4* bn4 = (const float4*)(pt + ((size_t)n * NF + g) * 8);
  float4 rpn = bn4[0], tpn = bn4[1];
  const float* rnp = (const float*)&rpn; const float* tnp = (const float*)&tpn;
  #pragma unroll
  for (int h = 0; h < NH; ++h) acc -= sc1[h] * rnp[h] + sc2[h] * tnp[h];
  acc *= (1.f / NH);

  am_s[w][g] = acc;   // wave-local LDS; no block barrier needed
  float o = x[(size_t)n * NF + g];
  #pragma unroll 8
  for (int f = 0; f < NF; ++f) o += am_s[w][f] * wout_s[f * NF + g];
  out[(size_t)n * NF + g] = o;
}

extern "C" void kernel_launch(void* const* d_in, const int* in_sizes, int n_in,
                              void* d_out, int out_size, void* d_ws, size_t ws_size,
                              hipStream_t stream) {
  const float* x    = (const float*)d_in[0];
  const int*   ei   = (const int*)d_in[1];
  // d_in[2] = edge_vec, unused by the reference
  const float* elen = (const float*)d_in[3];
  const float* Wp   = (const float*)d_in[4];
  const float* Wr   = (const float*)d_in[5];
  const float* Wt   = (const float*)d_in[6];
  const float* rsc  = (const float*)d_in[7];
  const float* tsc  = (const float*)d_in[8];
  const float* rdls = (const float*)d_in[9];
  const float* rtb  = (const float*)d_in[10];
  const float* rtw  = (const float*)d_in[11];
  const float* mixb = (const float*)d_in[12];
  const float* mixs = (const float*)d_in[13];
  const float* dW1  = (const float*)d_in[14];
  const float* db1  = (const float*)d_in[15];
  const float* dw2  = (const float*)d_in[16];
  const float* db2  = (const float*)d_in[17];
  const float* tW1  = (const float*)d_in[18];
  const float* tb1  = (const float*)d_in[19];
  const float* tw2  = (const float*)d_in[20];
  const float* tb2  = (const float*)d_in[21];
  const float* Wout = (const float*)d_in[22];

  int N = in_sizes[0] / NF;
  int E = in_sizes[3];

  float* p = (float*)d_ws;
  float* pt   = p; p += (size_t)N * NF * 8;   // [n][g][8]
  float* sr   = p; p += (size_t)N * NH;
  float* st   = p; p += (size_t)N * NH;
  float* doff = p; p += (size_t)N * NH;
  float* toff = p; p += (size_t)N * NH;
  float* crl  = p; p += (size_t)E * NH;       // CSR-ordered radial logits
  float* ctl  = p; p += (size_t)E * NH;       // CSR-ordered tangential logits
  float* cgv  = p; p += (size_t)E * NH;       // CSR-ordered mix gate
  int* snd    = (int*)p; p += E;              // CSR-ordered sender ids
  int* deg    = (int*)p; p += N;
  int* cursor = (int*)p; p += N;
  int* startp = (int*)p; p += N + 1;

  // K0: zero deg + cursor (contiguous)
  k_zero<<<(2 * N + 255) / 256, 256, 0, stream>>>(deg, 2 * N);
  // K0b: degree count
  k_count<<<(E + 255) / 256, 256, 0, stream>>>(ei, deg, E);
  // K1: tiled node pass (split by matrix)
  {
    dim3 grid((N + NT - 1) / NT, 3);
    k_proj<<<grid, 256, 0, stream>>>(x, Wp, Wr, Wt, rsc, tsc, dW1, db1, dw2, db2,
                                     tW1, tb1, tw2, tb2, rdls, rtb,
                                     pt, sr, st, doff, toff, N);
  }
  // K2: scan degrees -> CSR starts
  k_scan<<<1, 1024, 0, stream>>>(deg, startp, N);
  // K3: per-edge logits into CSR slots
  k_edge<<<(E + 255) / 256, 256, 0, stream>>>(ei, elen, (const float4*)sr, (const float4*)st,
                                              (const float4*)doff, (const float4*)toff,
                                              rtw, mixb, mixs, startp, cursor,
                                              (float4*)crl, (float4*)ctl, (float4*)cgv, snd, E);
  // K4: softmax + aggregate + output
  k_aggout<<<(N + 3) / 4, 256, 0, stream>>>(startp, snd, (const float4*)crl, (const float4*)ctl,
                                            (const float4*)cgv, pt, x, Wout, (float*)d_out, N);
}

// Round 15
// 178.488 us; speedup vs baseline: 2.0465x; 1.2891x over previous
//
#include <hip/hip_runtime.h>
#include <math.h>

#define NH 4
#define NF 64
#define NM 32
#define NT 16  // nodes per block in k_projm
#define SC 32  // elements per thread in k_scan (supports N <= 32768)

typedef __attribute__((ext_vector_type(8))) short bf16x8;
typedef __attribute__((ext_vector_type(4))) float f32x4;

__device__ __forceinline__ float softplusf(float v){ return fmaxf(v, 0.f) + log1pf(expf(-fabsf(v))); }
__device__ __forceinline__ float sigmoidf_(float v){ return 1.f / (1.f + expf(-v)); }
__device__ __forceinline__ unsigned short f2bf(float f) {
  unsigned u = __float_as_uint(f);
  u = u + 0x7FFFu + ((u >> 16) & 1u);   // round-to-nearest-even
  return (unsigned short)(u >> 16);
}

// ---------------- K0: zero deg + cursor ----------------
__global__ void k_zero(int* __restrict__ z, int n) {
  int i = blockIdx.x * blockDim.x + threadIdx.x;
  if (i < n) z[i] = 0;
}

// ---------------- K0b: degree count ----------------
__global__ void k_count(const int* __restrict__ ei, int* __restrict__ deg, int E) {
  int e = blockIdx.x * blockDim.x + threadIdx.x;
  if (e < E) atomicAdd(&deg[ei[E + e]], 1);
}

// ---------------- K0c: pack weights into MFMA B-fragment order (bf16) ----------------
// frag 0..95: proj  frag = ((q*4+h)*2+kb)*4+nb   (q: 0=Wp 1=Wr 2=Wt)
// frag 96..127: mlp frag = 96 + ((p*4+h)*2+kb)*2+nb  (p: 0=decay 1=temp)
// B-fragment layout: lane l holds B[kb*32 + (l>>4)*8 + j][nb*16 + (l&15)], j=0..7
__global__ void k_pack(const float* __restrict__ Wp, const float* __restrict__ Wr,
                       const float* __restrict__ Wt,
                       const float* __restrict__ dW1, const float* __restrict__ tW1,
                       unsigned short* __restrict__ Wpk) {
  int t = blockIdx.x * blockDim.x + threadIdx.x;   // 8192 threads
  int lane = t & 63;
  int frag = t >> 6;   // 0..127
  if (frag >= 128) return;
  if (frag < 96) {
    int nb = frag & 3, kb = (frag >> 2) & 1, h = (frag >> 3) & 3, q = frag >> 5;
    const float* W = (q == 0 ? Wp : (q == 1 ? Wr : Wt));
    int col = nb * 16 + (lane & 15);
    int krow = kb * 32 + (lane >> 4) * 8;
    #pragma unroll
    for (int j = 0; j < 8; ++j)
      Wpk[((size_t)frag * 64 + lane) * 8 + j] = f2bf(W[(size_t)h * NF * NF + (krow + j) * NF + col]);
  } else {
    int f2 = frag - 96;
    int nb = f2 & 1, kb = (f2 >> 1) & 1, h = (f2 >> 2) & 3, p2 = f2 >> 4;
    const float* W = (p2 == 0 ? dW1 : tW1);
    int col = nb * 16 + (lane & 15);
    int krow = kb * 32 + (lane >> 4) * 8;
    #pragma unroll
    for (int j = 0; j < 8; ++j)
      Wpk[((size_t)frag * 64 + lane) * 8 + j] = f2bf(W[(size_t)h * NF * NM + (krow + j) * NM + col]);
  }
}

// ---------------- K1: MFMA node pass ----------------
// grid = N/16 blocks x 256 thr (4 waves, wave = head h). 32 MFMAs per wave:
// 24 proj (3 mats x 4 col-tiles x 2 K) + 8 MLP. sr/st + decay/temp reduced via shfl.
__global__ __launch_bounds__(256)
void k_projm(const float* __restrict__ x, const unsigned short* __restrict__ Wpk,
             const float* __restrict__ rsc, const float* __restrict__ tsc,
             const float* __restrict__ db1, const float* __restrict__ dw2, const float* __restrict__ db2,
             const float* __restrict__ tb1, const float* __restrict__ tw2, const float* __restrict__ tb2,
             const float* __restrict__ rdls, const float* __restrict__ rtb,
             float* __restrict__ pt, float* __restrict__ sr, float* __restrict__ st,
             float* __restrict__ doff, float* __restrict__ toff, int N) {
  int n0 = blockIdx.x * NT;
  int tid = threadIdx.x;
  int h = tid >> 6, l = tid & 63;
  int lo = l & 15, hi = l >> 4;
  __shared__ __align__(16) unsigned short eps16[NH][16][72];  // bf16 ep, padded rows (144B)

  const bf16x8* W8 = (const bf16x8*)Wpk;

  // A fragments from x: lane l = row (n0+lo), k = kb*32 + hi*8 + j
  bf16x8 a[2];
  {
    int nr = n0 + lo; if (nr >= N) nr = N - 1;
    const float* xr = x + (size_t)nr * NF + hi * 8;
    #pragma unroll
    for (int kb = 0; kb < 2; ++kb) {
      float4 v0 = *(const float4*)(xr + kb * 32);
      float4 v1 = *(const float4*)(xr + kb * 32 + 4);
      bf16x8 aa;
      aa[0] = (short)f2bf(v0.x); aa[1] = (short)f2bf(v0.y);
      aa[2] = (short)f2bf(v0.z); aa[3] = (short)f2bf(v0.w);
      aa[4] = (short)f2bf(v1.x); aa[5] = (short)f2bf(v1.y);
      aa[6] = (short)f2bf(v1.z); aa[7] = (short)f2bf(v1.w);
      a[kb] = aa;
    }
  }

  float srp[4] = {0.f,0.f,0.f,0.f}, stp[4] = {0.f,0.f,0.f,0.f};
  // ---- projection GEMMs ----
  #pragma unroll
  for (int q = 0; q < 3; ++q) {
    #pragma unroll
    for (int nb = 0; nb < 4; ++nb) {
      f32x4 c = {0.f, 0.f, 0.f, 0.f};
      #pragma unroll
      for (int kb = 0; kb < 2; ++kb) {
        int frag = ((q * 4 + h) * 2 + kb) * 4 + nb;
        c = __builtin_amdgcn_mfma_f32_16x16x32_bf16(a[kb], W8[frag * 64 + l], c, 0, 0, 0);
      }
      int g = nb * 16 + lo;
      if (q == 0) {
        float rs = rsc[h * NF + g], ts = tsc[h * NF + g];
        #pragma unroll
        for (int r = 0; r < 4; ++r) {
          eps16[h][hi * 4 + r][g] = f2bf(c[r]);
          srp[r] += c[r] * rs;
          stp[r] += c[r] * ts;
        }
      } else {
        int row = (q - 1) * NH + h;
        #pragma unroll
        for (int r = 0; r < 4; ++r) {
          int n = n0 + hi * 4 + r;
          if (n < N) pt[((size_t)n * NF + g) * 8 + row] = c[r];
        }
      }
    }
  }
  // reduce sr/st over the 16-lane column group
  #pragma unroll
  for (int off = 1; off < 16; off <<= 1)
    #pragma unroll
    for (int r = 0; r < 4; ++r) { srp[r] += __shfl_xor(srp[r], off); stp[r] += __shfl_xor(stp[r], off); }
  if (lo == 0) {
    #pragma unroll
    for (int r = 0; r < 4; ++r) {
      int n = n0 + hi * 4 + r;
      if (n < N) { sr[n * NH + h] = srp[r]; st[n * NH + h] = stp[r]; }
    }
  }

  // ---- MLPs (A = ep bf16 from wave-local LDS) ----
  asm volatile("s_waitcnt lgkmcnt(0)" ::: "memory");
  bf16x8 ea[2];
  #pragma unroll
  for (int kb = 0; kb < 2; ++kb)
    ea[kb] = *(const bf16x8*)&eps16[h][lo][kb * 32 + hi * 8];

  float dpp[4] = {0.f,0.f,0.f,0.f}, tpp[4] = {0.f,0.f,0.f,0.f};
  #pragma unroll
  for (int p2 = 0; p2 < 2; ++p2) {
    #pragma unroll
    for (int nb = 0; nb < 2; ++nb) {
      f32x4 c = {0.f, 0.f, 0.f, 0.f};
      #pragma unroll
      for (int kb = 0; kb < 2; ++kb) {
        int frag = 96 + ((p2 * 4 + h) * 2 + kb) * 2 + nb;
        c = __builtin_amdgcn_mfma_f32_16x16x32_bf16(ea[kb], W8[frag * 64 + l], c, 0, 0, 0);
      }
      int m = nb * 16 + lo;
      float b1 = (p2 == 0 ? db1 : tb1)[h * NM + m];
      float w2 = (p2 == 0 ? dw2 : tw2)[h * NM + m];
      #pragma unroll
      for (int r = 0; r < 4; ++r) {
        float av = c[r] + b1;
        float sv = av * sigmoidf_(av) * w2;   // silu * w2
        if (p2 == 0) dpp[r] += sv; else tpp[r] += sv;
      }
    }
  }
  #pragma unroll
  for (int off = 1; off < 16; off <<= 1)
    #pragma unroll
    for (int r = 0; r < 4; ++r) { dpp[r] += __shfl_xor(dpp[r], off); tpp[r] += __shfl_xor(tpp[r], off); }
  if (lo == 0) {
    float dbase = db2[h] + softplusf(rdls[h]);
    float tbase = tb2[h] + rtb[h];
    #pragma unroll
    for (int r = 0; r < 4; ++r) {
      int n = n0 + hi * 4 + r;
      if (n < N) { doff[n * NH + h] = dpp[r] + dbase; toff[n * NH + h] = tpp[r] + tbase; }
    }
  }
}

// ---------------- K2: exclusive prefix scan (thread-serial + one tree) ----------------
__global__ void k_scan(const int* __restrict__ deg, int* __restrict__ start, int N) {
  __shared__ int sums[1024];
  int tid = threadIdx.x;
  int base = tid * SC;
  int local[SC];
  int s = 0;
  #pragma unroll
  for (int j = 0; j < SC; ++j) {
    int i = base + j;
    int v = (i < N) ? deg[i] : 0;
    local[j] = s;   // exclusive local prefix
    s += v;
  }
  sums[tid] = s;
  __syncthreads();
  for (int off = 1; off < 1024; off <<= 1) {
    int t = (tid >= off) ? sums[tid - off] : 0;
    __syncthreads();
    sums[tid] += t;
    __syncthreads();
  }
  int tbase = (tid > 0) ? sums[tid - 1] : 0;
  #pragma unroll
  for (int j = 0; j < SC; ++j) {
    int i = base + j;
    if (i < N) start[i] = tbase + local[j];
  }
  if (tid == 1023) start[N] = sums[1023];
}

// ---------------- K3: per-edge logits + gate, written in CSR order ----------------
__global__ void k_edge(const int* __restrict__ ei, const float* __restrict__ elen,
                       const float4* __restrict__ sr4, const float4* __restrict__ st4,
                       const float4* __restrict__ doff4, const float4* __restrict__ toff4,
                       const float* __restrict__ rtw,
                       const float* __restrict__ mixb, const float* __restrict__ mixs,
                       const int* __restrict__ start, int* __restrict__ cursor,
                       float4* __restrict__ crl, float4* __restrict__ ctl, float4* __restrict__ cgv,
                       int* __restrict__ snd, int E) {
  int e = blockIdx.x * blockDim.x + threadIdx.x;
  if (e >= E) return;
  int s = ei[e], r = ei[E + e];
  float len = elen[e];
  int slot = start[r] + atomicAdd(&cursor[r], 1);
  float4 a = sr4[s], b = sr4[r], c = st4[s], d = st4[r], dof = doff4[r], tof = toff4[r];
  const float* ap = (const float*)&a; const float* bp = (const float*)&b;
  const float* cp = (const float*)&c; const float* dp = (const float*)&d;
  const float* dofp = (const float*)&dof; const float* tofp = (const float*)&tof;
  float rlv[NH], tlv[NH], gv[NH];
  #pragma unroll
  for (int h = 0; h < NH; ++h) {
    float temp = softplusf(tofp[h] + rtw[h] * len);
    rlv[h] = (ap[h] - bp[h] - dofp[h] * len) / (temp + 1e-4f);
    tlv[h] = cp[h] - dp[h];
    gv[h] = sigmoidf_(mixb[h] + mixs[h] * len);
  }
  crl[slot] = make_float4(rlv[0], rlv[1], rlv[2], rlv[3]);
  ctl[slot] = make_float4(tlv[0], tlv[1], tlv[2], tlv[3]);
  cgv[slot] = make_float4(gv[0], gv[1], gv[2], gv[3]);
  snd[slot] = s;
}

// ---------------- K4: per-receiver softmax + gather-aggregate + Wout + residual ----------------
__global__ __launch_bounds__(256)
void k_aggout(const int* __restrict__ start, const int* __restrict__ snd,
              const float4* __restrict__ crl, const float4* __restrict__ ctl, const float4* __restrict__ cgv,
              const float* __restrict__ pt, const float* __restrict__ x,
              const float* __restrict__ Wout, float* __restrict__ out, int N) {
  __shared__ float wout_s[NF * NF];
  __shared__ float coef_s[4][64][8];
  __shared__ int   snd_s[4][64];
  __shared__ float am_s[4][NF];
  int tid = threadIdx.x;
  {
    const float4* w4 = (const float4*)Wout;
    float4* s4 = (float4*)wout_s;
    for (int i = tid; i < NF * NF / 4; i += 256) s4[i] = w4[i];
  }
  __syncthreads();   // only block-wide barrier; everything after is wave-local
  int w = tid >> 6, g = tid & 63;
  int n = blockIdx.x * 4 + w;
  if (n >= N) return;
  int i0 = start[n], i1 = start[n + 1];

  // pass A: per-head max (edge-parallel, lane = edge)
  float rm[NH] = {-1e30f, -1e30f, -1e30f, -1e30f};
  float tm[NH] = {-1e30f, -1e30f, -1e30f, -1e30f};
  for (int i = i0 + g; i < i1; i += 64) {
    float4 rv = crl[i], tv = ctl[i];
    const float* rp_ = (const float*)&rv; const float* tp_ = (const float*)&tv;
    #pragma unroll
    for (int h = 0; h < NH; ++h) { rm[h] = fmaxf(rm[h], rp_[h]); tm[h] = fmaxf(tm[h], tp_[h]); }
  }
  #pragma unroll
  for (int off = 32; off; off >>= 1)
    #pragma unroll
    for (int h = 0; h < NH; ++h) {
      rm[h] = fmaxf(rm[h], __shfl_xor(rm[h], off));
      tm[h] = fmaxf(tm[h], __shfl_xor(tm[h], off));
    }

  // pass B: per-head exp-sum
  float rs_[NH] = {0.f, 0.f, 0.f, 0.f}, ts_[NH] = {0.f, 0.f, 0.f, 0.f};
  for (int i = i0 + g; i < i1; i += 64) {
    float4 rv = crl[i], tv = ctl[i];
    const float* rp_ = (const float*)&rv; const float* tp_ = (const float*)&tv;
    #pragma unroll
    for (int h = 0; h < NH; ++h) { rs_[h] += expf(rp_[h] - rm[h]); ts_[h] += expf(tp_[h] - tm[h]); }
  }
  #pragma unroll
  for (int off = 32; off; off >>= 1)
    #pragma unroll
    for (int h = 0; h < NH; ++h) { rs_[h] += __shfl_xor(rs_[h], off); ts_[h] += __shfl_xor(ts_[h], off); }
  #pragma unroll
  for (int h = 0; h < NH; ++h) { rs_[h] = 1.f / (rs_[h] + 1e-9f); ts_[h] = 1.f / (ts_[h] + 1e-9f); }

  // pass C: coefficients (lane=edge) + gather-aggregate (lane=feature)
  float acc = 0.f;
  float sc1[NH] = {0.f, 0.f, 0.f, 0.f}, sc2[NH] = {0.f, 0.f, 0.f, 0.f};
  for (int base = i0; base < i1; base += 64) {
    int i = base + g;
    if (i < i1) {
      float4 rv = crl[i], tv = ctl[i], gv = cgv[i];
      const float* rp_ = (const float*)&rv; const float* tp_ = (const float*)&tv;
      const float* gp_ = (const float*)&gv;
      #pragma unroll
      for (int h = 0; h < NH; ++h) {
        float ar = expf(rp_[h] - rm[h]) * rs_[h];
        float at = expf(tp_[h] - tm[h]) * ts_[h];
        float gg = gp_[h];
        float ba = gg * ar + (1.f - gg) * at;
        float c1 = ba * gg, c2 = ba * (1.f - gg);
        coef_s[w][g][h] = c1; coef_s[w][g][4 + h] = c2;
        sc1[h] += c1; sc2[h] += c2;
      }
      snd_s[w][g] = snd[i];
    }
    int cnt = min(64, i1 - base);
    for (int j = 0; j < cnt; ++j) {
      int s = snd_s[w][j];
      const float4* b4 = (const float4*)(pt + ((size_t)s * NF + g) * 8);
      float4 rpv = b4[0], tpv = b4[1];
      const float* rpp = (const float*)&rpv; const float* tpp = (const float*)&tpv;
      #pragma unroll
      for (int h = 0; h < NH; ++h)
        acc += coef_s[w][j][h] * rpp[h] + coef_s[w][j][4 + h] * tpp[h];
    }
  }
  // reduce coefficient sums across the wave (each lane held its own edges' share)
  #pragma unroll
  for (int off = 32; off; off >>= 1)
    #pragma unroll
    for (int h = 0; h < NH; ++h) { sc1[h] += __shfl_xor(sc1[h], off); sc2[h] += __shfl_xor(sc2[h], off); }

  const float4* bn4 = (const float4*)(pt + ((size_t)n * NF + g) * 8);
  float4 rpn = bn4[0], tpn = bn4[1];
  const float* rnp = (const float*)&rpn; const float* tnp = (const float*)&tpn;
  #pragma unroll
  for (int h = 0; h < NH; ++h) acc -= sc1[h] * rnp[h] + sc2[h] * tnp[h];
  acc *= (1.f / NH);

  am_s[w][g] = acc;   // wave-local LDS; no block barrier needed
  float o = x[(size_t)n * NF + g];
  #pragma unroll 8
  for (int f = 0; f < NF; ++f) o += am_s[w][f] * wout_s[f * NF + g];
  out[(size_t)n * NF + g] = o;
}

extern "C" void kernel_launch(void* const* d_in, const int* in_sizes, int n_in,
                              void* d_out, int out_size, void* d_ws, size_t ws_size,
                              hipStream_t stream) {
  const float* x    = (const float*)d_in[0];
  const int*   ei   = (const int*)d_in[1];
  // d_in[2] = edge_vec, unused by the reference
  const float* elen = (const float*)d_in[3];
  const float* Wp   = (const float*)d_in[4];
  const float* Wr   = (const float*)d_in[5];
  const float* Wt   = (const float*)d_in[6];
  const float* rsc  = (const float*)d_in[7];
  const float* tsc  = (const float*)d_in[8];
  const float* rdls = (const float*)d_in[9];
  const float* rtb  = (const float*)d_in[10];
  const float* rtw  = (const float*)d_in[11];
  const float* mixb = (const float*)d_in[12];
  const float* mixs = (const float*)d_in[13];
  const float* dW1  = (const float*)d_in[14];
  const float* db1  = (const float*)d_in[15];
  const float* dw2  = (const float*)d_in[16];
  const float* db2  = (const float*)d_in[17];
  const float* tW1  = (const float*)d_in[18];
  const float* tb1  = (const float*)d_in[19];
  const float* tw2  = (const float*)d_in[20];
  const float* tb2  = (const float*)d_in[21];
  const float* Wout = (const float*)d_in[22];

  int N = in_sizes[0] / NF;
  int E = in_sizes[3];

  float* p = (float*)d_ws;
  unsigned short* Wpk = (unsigned short*)p; p += 32768;  // 128 fragments x 64 lanes x 8 bf16
  float* pt   = p; p += (size_t)N * NF * 8;   // [n][g][8]
  float* sr   = p; p += (size_t)N * NH;
  float* st   = p; p += (size_t)N * NH;
  float* doff = p; p += (size_t)N * NH;
  float* toff = p; p += (size_t)N * NH;
  float* crl  = p; p += (size_t)E * NH;       // CSR-ordered radial logits
  float* ctl  = p; p += (size_t)E * NH;       // CSR-ordered tangential logits
  float* cgv  = p; p += (size_t)E * NH;       // CSR-ordered mix gate
  int* snd    = (int*)p; p += E;              // CSR-ordered sender ids
  int* deg    = (int*)p; p += N;
  int* cursor = (int*)p; p += N;
  int* startp = (int*)p; p += N + 1;

  // K0: zero deg + cursor (contiguous)
  k_zero<<<(2 * N + 255) / 256, 256, 0, stream>>>(deg, 2 * N);
  // K0b: degree count
  k_count<<<(E + 255) / 256, 256, 0, stream>>>(ei, deg, E);
  // K0c: pack weights into MFMA fragments
  k_pack<<<32, 256, 0, stream>>>(Wp, Wr, Wt, dW1, tW1, Wpk);
  // K1: MFMA node pass
  k_projm<<<(N + NT - 1) / NT, 256, 0, stream>>>(x, Wpk, rsc, tsc, db1, dw2, db2,
                                                 tb1, tw2, tb2, rdls, rtb,
                                                 pt, sr, st, doff, toff, N);
  // K2: scan degrees -> CSR starts
  k_scan<<<1, 1024, 0, stream>>>(deg, startp, N);
  // K3: per-edge logits into CSR slots
  k_edge<<<(E + 255) / 256, 256, 0, stream>>>(ei, elen, (const float4*)sr, (const float4*)st,
                                              (const float4*)doff, (const float4*)toff,
                                              rtw, mixb, mixs, startp, cursor,
                                              (float4*)crl, (float4*)ctl, (float4*)cgv, snd, E);
  // K4: softmax + aggregate + output
  k_aggout<<<(N + 3) / 4, 256, 0, stream>>>(startp, snd, (const float4*)crl, (const float4*)ctl,
                                            (const float4*)cgv, pt, x, Wout, (float*)d_out, N);
}

// Round 17
// 152.034 us; speedup vs baseline: 2.4026x; 1.1740x over previous
//
#include <hip/hip_runtime.h>
#include <math.h>

#define NH 4
#define NF 64
#define NM 32
#define NT 16  // nodes per block in k_projm
#define SC 32  // elements per thread in k_scan (supports N <= 32768)

typedef __attribute__((ext_vector_type(8))) short bf16x8;
typedef __attribute__((ext_vector_type(4))) float f32x4;

__device__ __forceinline__ float softplusf(float v){ return fmaxf(v, 0.f) + log1pf(expf(-fabsf(v))); }
__device__ __forceinline__ float sigmoidf_(float v){ return 1.f / (1.f + expf(-v)); }
__device__ __forceinline__ unsigned short f2bf(float f) {
  unsigned u = __float_as_uint(f);
  u = u + 0x7FFFu + ((u >> 16) & 1u);   // round-to-nearest-even
  return (unsigned short)(u >> 16);
}
__device__ __forceinline__ float bflo(unsigned u){ return __uint_as_float(u << 16); }
__device__ __forceinline__ float bfhi(unsigned u){ return __uint_as_float(u & 0xFFFF0000u); }

// ---------------- K0: zero deg + cursor ----------------
__global__ void k_zero(int* __restrict__ z, int n) {
  int i = blockIdx.x * blockDim.x + threadIdx.x;
  if (i < n) z[i] = 0;
}

// ---------------- K0b: degree count ----------------
__global__ void k_count(const int* __restrict__ ei, int* __restrict__ deg, int E) {
  int e = blockIdx.x * blockDim.x + threadIdx.x;
  if (e < E) atomicAdd(&deg[ei[E + e]], 1);
}

// ---------------- K0c: pack weights into MFMA B-fragment order (bf16) ----------------
// frag 0..95: proj  frag = ((q*4+h)*2+kb)*4+nb   (q: 0=Wp 1=Wr 2=Wt)
// frag 96..127: mlp frag = 96 + ((p*4+h)*2+kb)*2+nb  (p: 0=decay 1=temp)
// B-fragment layout: lane l holds B[kb*32 + (l>>4)*8 + j][nb*16 + (l&15)], j=0..7
__global__ void k_pack(const float* __restrict__ Wp, const float* __restrict__ Wr,
                       const float* __restrict__ Wt,
                       const float* __restrict__ dW1, const float* __restrict__ tW1,
                       unsigned short* __restrict__ Wpk) {
  int t = blockIdx.x * blockDim.x + threadIdx.x;   // 8192 threads
  int lane = t & 63;
  int frag = t >> 6;   // 0..127
  if (frag >= 128) return;
  if (frag < 96) {
    int nb = frag & 3, kb = (frag >> 2) & 1, h = (frag >> 3) & 3, q = frag >> 5;
    const float* W = (q == 0 ? Wp : (q == 1 ? Wr : Wt));
    int col = nb * 16 + (lane & 15);
    int krow = kb * 32 + (lane >> 4) * 8;
    #pragma unroll
    for (int j = 0; j < 8; ++j)
      Wpk[((size_t)frag * 64 + lane) * 8 + j] = f2bf(W[(size_t)h * NF * NF + (krow + j) * NF + col]);
  } else {
    int f2 = frag - 96;
    int nb = f2 & 1, kb = (f2 >> 1) & 1, h = (f2 >> 2) & 3, p2 = f2 >> 4;
    const float* W = (p2 == 0 ? dW1 : tW1);
    int col = nb * 16 + (lane & 15);
    int krow = kb * 32 + (lane >> 4) * 8;
    #pragma unroll
    for (int j = 0; j < 8; ++j)
      Wpk[((size_t)frag * 64 + lane) * 8 + j] = f2bf(W[(size_t)h * NF * NM + (krow + j) * NM + col]);
  }
}

// ---------------- K1: MFMA node pass (pt stored bf16) ----------------
__global__ __launch_bounds__(256)
void k_projm(const float* __restrict__ x, const unsigned short* __restrict__ Wpk,
             const float* __restrict__ rsc, const float* __restrict__ tsc,
             const float* __restrict__ db1, const float* __restrict__ dw2, const float* __restrict__ db2,
             const float* __restrict__ tb1, const float* __restrict__ tw2, const float* __restrict__ tb2,
             const float* __restrict__ rdls, const float* __restrict__ rtb,
             unsigned short* __restrict__ ptb, float* __restrict__ sr, float* __restrict__ st,
             float* __restrict__ doff, float* __restrict__ toff, int N) {
  int n0 = blockIdx.x * NT;
  int tid = threadIdx.x;
  int h = tid >> 6, l = tid & 63;
  int lo = l & 15, hi = l >> 4;
  __shared__ __align__(16) unsigned short eps16[NH][16][72];  // bf16 ep, padded rows (144B)

  const bf16x8* W8 = (const bf16x8*)Wpk;

  // A fragments from x: lane l = row (n0+lo), k = kb*32 + hi*8 + j
  bf16x8 a[2];
  {
    int nr = n0 + lo; if (nr >= N) nr = N - 1;
    const float* xr = x + (size_t)nr * NF + hi * 8;
    #pragma unroll
    for (int kb = 0; kb < 2; ++kb) {
      float4 v0 = *(const float4*)(xr + kb * 32);
      float4 v1 = *(const float4*)(xr + kb * 32 + 4);
      bf16x8 aa;
      aa[0] = (short)f2bf(v0.x); aa[1] = (short)f2bf(v0.y);
      aa[2] = (short)f2bf(v0.z); aa[3] = (short)f2bf(v0.w);
      aa[4] = (short)f2bf(v1.x); aa[5] = (short)f2bf(v1.y);
      aa[6] = (short)f2bf(v1.z); aa[7] = (short)f2bf(v1.w);
      a[kb] = aa;
    }
  }

  float srp[4] = {0.f,0.f,0.f,0.f}, stp[4] = {0.f,0.f,0.f,0.f};
  // ---- projection GEMMs ----
  #pragma unroll
  for (int q = 0; q < 3; ++q) {
    #pragma unroll
    for (int nb = 0; nb < 4; ++nb) {
      f32x4 c = {0.f, 0.f, 0.f, 0.f};
      #pragma unroll
      for (int kb = 0; kb < 2; ++kb) {
        int frag = ((q * 4 + h) * 2 + kb) * 4 + nb;
        c = __builtin_amdgcn_mfma_f32_16x16x32_bf16(a[kb], W8[frag * 64 + l], c, 0, 0, 0);
      }
      int g = nb * 16 + lo;
      if (q == 0) {
        float rs = rsc[h * NF + g], ts = tsc[h * NF + g];
        #pragma unroll
        for (int r = 0; r < 4; ++r) {
          eps16[h][hi * 4 + r][g] = f2bf(c[r]);
          srp[r] += c[r] * rs;
          stp[r] += c[r] * ts;
        }
      } else {
        int row = (q - 1) * NH + h;
        #pragma unroll
        for (int r = 0; r < 4; ++r) {
          int n = n0 + hi * 4 + r;
          if (n < N) ptb[((size_t)n * NF + g) * 8 + row] = f2bf(c[r]);
        }
      }
    }
  }
  // reduce sr/st over the 16-lane column group
  #pragma unroll
  for (int off = 1; off < 16; off <<= 1)
    #pragma unroll
    for (int r = 0; r < 4; ++r) { srp[r] += __shfl_xor(srp[r], off); stp[r] += __shfl_xor(stp[r], off); }
  if (lo == 0) {
    #pragma unroll
    for (int r = 0; r < 4; ++r) {
      int n = n0 + hi * 4 + r;
      if (n < N) { sr[n * NH + h] = srp[r]; st[n * NH + h] = stp[r]; }
    }
  }

  // ---- MLPs (A = ep bf16 from wave-local LDS) ----
  asm volatile("s_waitcnt lgkmcnt(0)" ::: "memory");
  bf16x8 ea[2];
  #pragma unroll
  for (int kb = 0; kb < 2; ++kb)
    ea[kb] = *(const bf16x8*)&eps16[h][lo][kb * 32 + hi * 8];

  float dpp[4] = {0.f,0.f,0.f,0.f}, tpp[4] = {0.f,0.f,0.f,0.f};
  #pragma unroll
  for (int p2 = 0; p2 < 2; ++p2) {
    #pragma unroll
    for (int nb = 0; nb < 2; ++nb) {
      f32x4 c = {0.f, 0.f, 0.f, 0.f};
      #pragma unroll
      for (int kb = 0; kb < 2; ++kb) {
        int frag = 96 + ((p2 * 4 + h) * 2 + kb) * 2 + nb;
        c = __builtin_amdgcn_mfma_f32_16x16x32_bf16(ea[kb], W8[frag * 64 + l], c, 0, 0, 0);
      }
      int m = nb * 16 + lo;
      float b1 = (p2 == 0 ? db1 : tb1)[h * NM + m];
      float w2 = (p2 == 0 ? dw2 : tw2)[h * NM + m];
      #pragma unroll
      for (int r = 0; r < 4; ++r) {
        float av = c[r] + b1;
        float sv = av * sigmoidf_(av) * w2;   // silu * w2
        if (p2 == 0) dpp[r] += sv; else tpp[r] += sv;
      }
    }
  }
  #pragma unroll
  for (int off = 1; off < 16; off <<= 1)
    #pragma unroll
    for (int r = 0; r < 4; ++r) { dpp[r] += __shfl_xor(dpp[r], off); tpp[r] += __shfl_xor(tpp[r], off); }
  if (lo == 0) {
    float dbase = db2[h] + softplusf(rdls[h]);
    float tbase = tb2[h] + rtb[h];
    #pragma unroll
    for (int r = 0; r < 4; ++r) {
      int n = n0 + hi * 4 + r;
      if (n < N) { doff[n * NH + h] = dpp[r] + dbase; toff[n * NH + h] = tpp[r] + tbase; }
    }
  }
}

// ---------------- K2: exclusive prefix scan (thread-serial + one tree) ----------------
__global__ void k_scan(const int* __restrict__ deg, int* __restrict__ start, int N) {
  __shared__ int sums[1024];
  int tid = threadIdx.x;
  int base = tid * SC;
  int local[SC];
  int s = 0;
  #pragma unroll
  for (int j = 0; j < SC; ++j) {
    int i = base + j;
    int v = (i < N) ? deg[i] : 0;
    local[j] = s;   // exclusive local prefix
    s += v;
  }
  sums[tid] = s;
  __syncthreads();
  for (int off = 1; off < 1024; off <<= 1) {
    int t = (tid >= off) ? sums[tid - off] : 0;
    __syncthreads();
    sums[tid] += t;
    __syncthreads();
  }
  int tbase = (tid > 0) ? sums[tid - 1] : 0;
  #pragma unroll
  for (int j = 0; j < SC; ++j) {
    int i = base + j;
    if (i < N) start[i] = tbase + local[j];
  }
  if (tid == 1023) start[N] = sums[1023];
}

// ---------------- K3: per-edge logits + gate, written in CSR order ----------------
__global__ void k_edge(const int* __restrict__ ei, const float* __restrict__ elen,
                       const float4* __restrict__ sr4, const float4* __restrict__ st4,
                       const float4* __restrict__ doff4, const float4* __restrict__ toff4,
                       const float* __restrict__ rtw,
                       const float* __restrict__ mixb, const float* __restrict__ mixs,
                       const int* __restrict__ start, int* __restrict__ cursor,
                       float4* __restrict__ crl, float4* __restrict__ ctl, float4* __restrict__ cgv,
                       int* __restrict__ snd, int E) {
  int e = blockIdx.x * blockDim.x + threadIdx.x;
  if (e >= E) return;
  int s = ei[e], r = ei[E + e];
  float len = elen[e];
  int slot = start[r] + atomicAdd(&cursor[r], 1);
  float4 a = sr4[s], b = sr4[r], c = st4[s], d = st4[r], dof = doff4[r], tof = toff4[r];
  const float* ap = (const float*)&a; const float* bp = (const float*)&b;
  const float* cp = (const float*)&c; const float* dp = (const float*)&d;
  const float* dofp = (const float*)&dof; const float* tofp = (const float*)&tof;
  float rlv[NH], tlv[NH], gv[NH];
  #pragma unroll
  for (int h = 0; h < NH; ++h) {
    float temp = softplusf(tofp[h] + rtw[h] * len);
    rlv[h] = (ap[h] - bp[h] - dofp[h] * len) / (temp + 1e-4f);
    tlv[h] = cp[h] - dp[h];
    gv[h] = sigmoidf_(mixb[h] + mixs[h] * len);
  }
  crl[slot] = make_float4(rlv[0], rlv[1], rlv[2], rlv[3]);
  ctl[slot] = make_float4(tlv[0], tlv[1], tlv[2], tlv[3]);
  cgv[slot] = make_float4(gv[0], gv[1], gv[2], gv[3]);
  snd[slot] = s;
}

// ---------------- K4: per-receiver softmax + gather-aggregate + Wout + residual ----------------
__global__ __launch_bounds__(256)
void k_aggout(const int* __restrict__ start, const int* __restrict__ snd,
              const float4* __restrict__ crl, const float4* __restrict__ ctl, const float4* __restrict__ cgv,
              const unsigned short* __restrict__ ptb, const float* __restrict__ x,
              const float* __restrict__ Wout, float* __restrict__ out, int N) {
  __shared__ float wout_s[NF * NF];
  __shared__ float coef_s[4][64][8];
  __shared__ int   snd_s[4][64];
  __shared__ float am_s[4][NF];
  int tid = threadIdx.x;
  {
    const float4* w4 = (const float4*)Wout;
    float4* s4 = (float4*)wout_s;
    for (int i = tid; i < NF * NF / 4; i += 256) s4[i] = w4[i];
  }
  __syncthreads();   // only block-wide barrier; everything after is wave-local
  int w = tid >> 6, g = tid & 63;
  int n = blockIdx.x * 4 + w;
  if (n >= N) return;
  int i0 = start[n], i1 = start[n + 1];

  // pass A: per-head max (edge-parallel, lane = edge)
  float rm[NH] = {-1e30f, -1e30f, -1e30f, -1e30f};
  float tm[NH] = {-1e30f, -1e30f, -1e30f, -1e30f};
  for (int i = i0 + g; i < i1; i += 64) {
    float4 rv = crl[i], tv = ctl[i];
    const float* rp_ = (const float*)&rv; const float* tp_ = (const float*)&tv;
    #pragma unroll
    for (int h = 0; h < NH; ++h) { rm[h] = fmaxf(rm[h], rp_[h]); tm[h] = fmaxf(tm[h], tp_[h]); }
  }
  #pragma unroll
  for (int off = 32; off; off >>= 1)
    #pragma unroll
    for (int h = 0; h < NH; ++h) {
      rm[h] = fmaxf(rm[h], __shfl_xor(rm[h], off));
      tm[h] = fmaxf(tm[h], __shfl_xor(tm[h], off));
    }

  // pass B: per-head exp-sum
  float rs_[NH] = {0.f, 0.f, 0.f, 0.f}, ts_[NH] = {0.f, 0.f, 0.f, 0.f};
  for (int i = i0 + g; i < i1; i += 64) {
    float4 rv = crl[i], tv = ctl[i];
    const float* rp_ = (const float*)&rv; const float* tp_ = (const float*)&tv;
    #pragma unroll
    for (int h = 0; h < NH; ++h) { rs_[h] += expf(rp_[h] - rm[h]); ts_[h] += expf(tp_[h] - tm[h]); }
  }
  #pragma unroll
  for (int off = 32; off; off >>= 1)
    #pragma unroll
    for (int h = 0; h < NH; ++h) { rs_[h] += __shfl_xor(rs_[h], off); ts_[h] += __shfl_xor(ts_[h], off); }
  #pragma unroll
  for (int h = 0; h < NH; ++h) { rs_[h] = 1.f / (rs_[h] + 1e-9f); ts_[h] = 1.f / (ts_[h] + 1e-9f); }

  // pass C: coefficients (lane=edge) + gather-aggregate (lane=feature, bf16 pt)
  float acc = 0.f;
  float sc1[NH] = {0.f, 0.f, 0.f, 0.f}, sc2[NH] = {0.f, 0.f, 0.f, 0.f};
  for (int base = i0; base < i1; base += 64) {
    int i = base + g;
    if (i < i1) {
      float4 rv = crl[i], tv = ctl[i], gv = cgv[i];
      const float* rp_ = (const float*)&rv; const float* tp_ = (const float*)&tv;
      const float* gp_ = (const float*)&gv;
      #pragma unroll
      for (int h = 0; h < NH; ++h) {
        float ar = expf(rp_[h] - rm[h]) * rs_[h];
        float at = expf(tp_[h] - tm[h]) * ts_[h];
        float gg = gp_[h];
        float ba = gg * ar + (1.f - gg) * at;
        float c1 = ba * gg, c2 = ba * (1.f - gg);
        coef_s[w][g][h] = c1; coef_s[w][g][4 + h] = c2;
        sc1[h] += c1; sc2[h] += c2;
      }
      snd_s[w][g] = snd[i];
    }
    int cnt = min(64, i1 - base);
    for (int j = 0; j < cnt; ++j) {
      int s = snd_s[w][j];
      uint4 uv = *(const uint4*)(ptb + ((size_t)s * NF + g) * 8);  // 16B: 8 bf16
      acc += coef_s[w][j][0] * bflo(uv.x) + coef_s[w][j][1] * bfhi(uv.x)
           + coef_s[w][j][2] * bflo(uv.y) + coef_s[w][j][3] * bfhi(uv.y)
           + coef_s[w][j][4] * bflo(uv.z) + coef_s[w][j][5] * bfhi(uv.z)
           + coef_s[w][j][6] * bflo(uv.w) + coef_s[w][j][7] * bfhi(uv.w);
    }
  }
  // reduce coefficient sums across the wave (each lane held its own edges' share)
  #pragma unroll
  for (int off = 32; off; off >>= 1)
    #pragma unroll
    for (int h = 0; h < NH; ++h) { sc1[h] += __shfl_xor(sc1[h], off); sc2[h] += __shfl_xor(sc2[h], off); }

  {
    uint4 uv = *(const uint4*)(ptb + ((size_t)n * NF + g) * 8);
    acc -= sc1[0] * bflo(uv.x) + sc1[1] * bfhi(uv.x)
         + sc1[2] * bflo(uv.y) + sc1[3] * bfhi(uv.y)
         + sc2[0] * bflo(uv.z) + sc2[1] * bfhi(uv.z)
         + sc2[2] * bflo(uv.w) + sc2[3] * bfhi(uv.w);
  }
  acc *= (1.f / NH);

  am_s[w][g] = acc;   // wave-local LDS; no block barrier needed
  float o = x[(size_t)n * NF + g];
  #pragma unroll 8
  for (int f = 0; f < NF; ++f) o += am_s[w][f] * wout_s[f * NF + g];
  out[(size_t)n * NF + g] = o;
}

extern "C" void kernel_launch(void* const* d_in, const int* in_sizes, int n_in,
                              void* d_out, int out_size, void* d_ws, size_t ws_size,
                              hipStream_t stream) {
  const float* x    = (const float*)d_in[0];
  const int*   ei   = (const int*)d_in[1];
  // d_in[2] = edge_vec, unused by the reference
  const float* elen = (const float*)d_in[3];
  const float* Wp   = (const float*)d_in[4];
  const float* Wr   = (const float*)d_in[5];
  const float* Wt   = (const float*)d_in[6];
  const float* rsc  = (const float*)d_in[7];
  const float* tsc  = (const float*)d_in[8];
  const float* rdls = (const float*)d_in[9];
  const float* rtb  = (const float*)d_in[10];
  const float* rtw  = (const float*)d_in[11];
  const float* mixb = (const float*)d_in[12];
  const float* mixs = (const float*)d_in[13];
  const float* dW1  = (const float*)d_in[14];
  const float* db1  = (const float*)d_in[15];
  const float* dw2  = (const float*)d_in[16];
  const float* db2  = (const float*)d_in[17];
  const float* tW1  = (const float*)d_in[18];
  const float* tb1  = (const float*)d_in[19];
  const float* tw2  = (const float*)d_in[20];
  const float* tb2  = (const float*)d_in[21];
  const float* Wout = (const float*)d_in[22];

  int N = in_sizes[0] / NF;
  int E = in_sizes[3];

  float* p = (float*)d_ws;
  unsigned short* Wpk = (unsigned short*)p; p += 32768;  // 128 frag x 64 lanes x 8 bf16 = 131072 B
  unsigned short* ptb = (unsigned short*)p; p += (size_t)N * NF * 8 / 2;  // [n][g][8] bf16
  float* sr   = p; p += (size_t)N * NH;
  float* st   = p; p += (size_t)N * NH;
  float* doff = p; p += (size_t)N * NH;
  float* toff = p; p += (size_t)N * NH;
  float* crl  = p; p += (size_t)E * NH;       // CSR-ordered radial logits
  float* ctl  = p; p += (size_t)E * NH;       // CSR-ordered tangential logits
  float* cgv  = p; p += (size_t)E * NH;       // CSR-ordered mix gate
  int* snd    = (int*)p; p += E;              // CSR-ordered sender ids
  int* deg    = (int*)p; p += N;
  int* cursor = (int*)p; p += N;
  int* startp = (int*)p; p += N + 1;

  // K0: zero deg + cursor (contiguous)
  k_zero<<<(2 * N + 255) / 256, 256, 0, stream>>>(deg, 2 * N);
  // K0b: degree count
  k_count<<<(E + 255) / 256, 256, 0, stream>>>(ei, deg, E);
  // K0c: pack weights into MFMA fragments
  k_pack<<<32, 256, 0, stream>>>(Wp, Wr, Wt, dW1, tW1, Wpk);
  // K1: MFMA node pass
  k_projm<<<(N + NT - 1) / NT, 256, 0, stream>>>(x, Wpk, rsc, tsc, db1, dw2, db2,
                                                 tb1, tw2, tb2, rdls, rtb,
                                                 ptb, sr, st, doff, toff, N);
  // K2: scan degrees -> CSR starts
  k_scan<<<1, 1024, 0, stream>>>(deg, startp, N);
  // K3: per-edge logits into CSR slots
  k_edge<<<(E + 255) / 256, 256, 0, stream>>>(ei, elen, (const float4*)sr, (const float4*)st,
                                              (const float4*)doff, (const float4*)toff,
                                              rtw, mixb, mixs, startp, cursor,
                                              (float4*)crl, (float4*)ctl, (float4*)cgv, snd, E);
  // K4: softmax + aggregate + output
  k_aggout<<<(N + 3) / 4, 256, 0, stream>>>(startp, snd, (const float4*)crl, (const float4*)ctl,
                                            (const float4*)cgv, ptb, x, Wout, (float*)d_out, N);
}